// Round 23
// baseline (229.286 us; speedup 1.0000x reference)
//
#include <hip/hip_runtime.h>
#include <hip/hip_bf16.h>
#include <math.h>

#define NLAT 256
#define NLON 512
#define LMAX 256
#define MMAX 257
#define BC   128

#define X_ELEMS 33554432
#define W_ELEMS 33685504
#define W_BYTES (W_ELEMS * 4LL)

#define FM    288                      // padded m rows for F
#define F_BYTES  ((size_t)2*FM*512*2)                    // 589,824
#define A_BYTES  ((size_t)4*BC*MMAX*NLAT*2)              // 67,371,008
#define OUTS_BYTES ((size_t)MMAX*2*BC*LMAX*2)            // 33,685,504
#define WBF_BYTES ((size_t)W_ELEMS*2)                    // 67,371,008

typedef short bf16x8 __attribute__((ext_vector_type(8)));
typedef float f32x4  __attribute__((ext_vector_type(4)));

__device__ __forceinline__ unsigned int bfpack2(float a, float b) {
    unsigned short lo = __builtin_bit_cast(unsigned short, __float2bfloat16(a));
    unsigned short hi = __builtin_bit_cast(unsigned short, __float2bfloat16(b));
    return (unsigned int)lo | ((unsigned int)hi << 16);
}
__device__ __forceinline__ unsigned short bf16bits(float a) {
    return __builtin_bit_cast(unsigned short, __float2bfloat16(a));
}
__device__ __forceinline__ void gload16(const void* g, void* l) {
    __builtin_amdgcn_global_load_lds(
        (const __attribute__((address_space(1))) unsigned int*)g,
        (__attribute__((address_space(3))) unsigned int*)l, 16, 0, 0);
}

// ---------------------------------------------------------------------------
// K0: build DFT matrix F[o][mm][n] bf16, scale 2*pi/512 folded in.
// ---------------------------------------------------------------------------
__global__ __launch_bounds__(256) void f_init(unsigned short* __restrict__ F)
{
    int mm = blockIdx.x, o = blockIdx.y, t = threadIdx.x;
    const float s = 6.283185307179586f / 512.0f;
    for (int c = 0; c < 2; ++c) {
        int n = t * 2 + c;
        float val = 0.0f;
        if (mm < MMAX) {
            int j = (mm * n) & 511;
            float ang = 6.283185307179586f * (float)j / 512.0f;
            float sn, cs; __sincosf(ang, &sn, &cs);
            val = (o == 0) ? s * cs : -s * sn;
        }
        F[((size_t)o * FM + mm) * 512 + n] =
            __builtin_bit_cast(unsigned short, __float2bfloat16(val));
    }
}

// ---------------------------------------------------------------------------
// K1 v11: DFT via MFMA (r21-validated core) + optional w->bf16 conversion
// epilogue (each of the 512 blocks converts a 65,792-elem slice; hides in
// this kernel's latency bubbles, hbm only ~18% busy).
// ---------------------------------------------------------------------------
__global__ __launch_bounds__(512, 1) void dft_mfma(const float* __restrict__ x,
                                                   const unsigned short* __restrict__ F,
                                                   unsigned short* __restrict__ aout,
                                                   const float* __restrict__ w,
                                                   unsigned short* __restrict__ wbf)
{
    __shared__ __align__(16) unsigned char fl[2][32768];   // 64KB; prologue uses as xl
    unsigned char* xl = (unsigned char*)fl;

    int bcc = blockIdx.x;           // 0..255
    int kh  = blockIdx.y;           // 0..1
    int bc = bcc >> 1, comp = bcc & 1;
    int t = threadIdx.x;
    int wid = t >> 6, lane = t & 63;

    int o = wid >> 2, kt = wid & 3;
    int r15 = lane & 15, hi = lane >> 4;
    int klocal = kt * 16 + r15;
    unsigned braw = (unsigned)klocal * 1024u;
    unsigned bswz = (unsigned)(klocal & 15) << 4;

    bf16x8 barr0[16], barr1[16];
    #pragma unroll
    for (int s = 0; s < 2; ++s) {
        const float* xg = x + ((size_t)bcc * NLAT + kh * 128 + s * 64) * NLON;
        #pragma unroll
        for (int p = 0; p < 8; ++p) {
            int row = wid * 8 + p;
            const float* src = xg + (size_t)row * NLON + lane * 8;
            float4 f0 = *(const float4*)(src);
            float4 f1 = *(const float4*)(src + 4);
            uint4 v;
            v.x = bfpack2(f0.x, f0.y); v.y = bfpack2(f0.z, f0.w);
            v.z = bfpack2(f1.x, f1.y); v.w = bfpack2(f1.z, f1.w);
            unsigned off = ((unsigned)row * 1024u + (unsigned)lane * 16u)
                           ^ ((unsigned)(row & 15) << 4);
            *(uint4*)(xl + off) = v;
        }
        __syncthreads();
        #pragma unroll
        for (int nt = 0; nt < 16; ++nt) {
            unsigned c0 = (unsigned)(nt * 64 + hi * 16);
            bf16x8 v = *(const bf16x8*)(xl + ((braw + c0) ^ bswz));
            if (s == 0) barr0[nt] = v; else barr1[nt] = v;
        }
        __syncthreads();
    }

    const unsigned char* Fb = (const unsigned char*)F;
    unsigned gcol = ((unsigned)lane * 16u);

    #define STAGE_F(buf, mt)                                                  \
        {                                                                     \
            _Pragma("unroll")                                                 \
            for (int p = 0; p < 4; ++p) {                                     \
                int fr = wid * 4 + p;                                         \
                int o2 = fr >> 4, mr = fr & 15;                               \
                size_t grow = (size_t)o2 * FM + (mt) * 16 + mr;               \
                const void* g = Fb + grow * 1024u                             \
                                + (gcol ^ ((unsigned)(fr & 15) << 4));        \
                gload16(g, (unsigned char*)fl[buf] + (unsigned)fr * 1024u);   \
            }                                                                 \
        }

    STAGE_F(0, 0);
    __syncthreads();

    unsigned arow = (unsigned)(o * 16 + r15);
    unsigned abase = arow * 1024u;
    unsigned aswz = (unsigned)r15 << 4;
    unsigned short* ao = aout;
    int v = comp * 2 + o;

    for (int mt = 0; mt < 17; ++mt) {
        int cur = mt & 1;
        if (mt < 16) STAGE_F(cur ^ 1, mt + 1);

        const unsigned char* fb = fl[cur];
        f32x4 accA0 = {0.f,0.f,0.f,0.f}, accA1 = {0.f,0.f,0.f,0.f};
        f32x4 accB0 = {0.f,0.f,0.f,0.f}, accB1 = {0.f,0.f,0.f,0.f};
        #pragma unroll
        for (int nt = 0; nt < 16; nt += 2) {
            unsigned c0 = (unsigned)(nt * 64 + hi * 16);
            bf16x8 a0 = *(const bf16x8*)(fb + ((abase + c0)       ^ aswz));
            bf16x8 a1 = *(const bf16x8*)(fb + ((abase + c0 + 64u) ^ aswz));
            accA0 = __builtin_amdgcn_mfma_f32_16x16x32_bf16(a0, barr0[nt],     accA0, 0, 0, 0);
            accB0 = __builtin_amdgcn_mfma_f32_16x16x32_bf16(a0, barr1[nt],     accB0, 0, 0, 0);
            accA1 = __builtin_amdgcn_mfma_f32_16x16x32_bf16(a1, barr0[nt + 1], accA1, 0, 0, 0);
            accB1 = __builtin_amdgcn_mfma_f32_16x16x32_bf16(a1, barr1[nt + 1], accB1, 0, 0, 0);
        }
        #pragma unroll
        for (int j = 0; j < 4; ++j) {
            accA0[j] += accA1[j];
            accB0[j] += accB1[j];
        }

        #pragma unroll
        for (int j = 0; j < 4; ++j) {
            int mm0 = mt * 16 + hi * 4 + j;
            if (mm0 < MMAX) {
                size_t base = (((size_t)v * BC + bc) * MMAX + mm0) * NLAT + kh * 128;
                ao[base + klocal]      = bf16bits(accA0[j]);
                ao[base + klocal + 64] = bf16bits(accB0[j]);
            }
        }
        __syncthreads();
    }
    #undef STAGE_F

    // ---- optional epilogue: convert this block's w slice to bf16
    // slice = 65,792 elems = 8224 units of 8; 512 slices cover W_ELEMS exactly.
    if (wbf) {
        int slice = bcc * 2 + kh;                 // 0..511
        size_t base = (size_t)slice * 65792;
        for (int u = t; u < 8224; u += 512) {
            size_t idx = base + (size_t)u * 8;
            float4 f0 = *(const float4*)(w + idx);
            float4 f1 = *(const float4*)(w + idx + 4);
            uint4 vv;
            vv.x = bfpack2(f0.x, f0.y); vv.y = bfpack2(f0.z, f0.w);
            vv.z = bfpack2(f1.x, f1.y); vv.w = bfpack2(f1.z, f1.w);
            *(uint4*)(wbf + idx) = vv;
        }
    }
}

// ---------------------------------------------------------------------------
// K2 v5: contraction via MFMA — r20/21-validated v3 skeleton, but B staged
// from the bf16 w copy (halves per-iter staged bytes 48KB -> 24KB).
// Phase-split accs: accLo (kt2 0-7, w0), accHi (kt2 8-15, w1);
//   out0 = accLo - accHi ; out1 = -(accLo + accHi).
// grid (m:257, lh:2), 512 thr = 8 waves (o:2, h:2, q:2).
// ---------------------------------------------------------------------------
template <int MODE>
__global__ __launch_bounds__(512, 1) void contract_bf(const unsigned short* __restrict__ a,
                                                      const unsigned short* __restrict__ wbf,
                                                      void* __restrict__ outv)
{
    __shared__ __align__(16) unsigned char Ab[2][16384];   // [pl*128+bcr][32k] 64B rows, swz
    __shared__ __align__(16) unsigned char Bb[2][10240];   // [128 l][32 k] 80B rows
    int m  = blockIdx.x;
    int lh = blockIdx.y;            // 0..1
    int t = threadIdx.x;
    int wid = t >> 6, lane = t & 63;
    int o = wid >> 2, h = (wid >> 1) & 1, q = wid & 1;
    int r15 = lane & 15, hi = lane >> 4;
    int l0 = lh * 128;

    f32x4 accLo[4][4] = {};
    f32x4 accHi[4][4] = {};

    int bcr = t >> 2, ch4 = t & 3;
    int lB  = t >> 2, chB = t & 3;

    #define STAGE_A(buf, kt)                                                    \
        {                                                                       \
            int ph_ = (kt) >> 3;                                                \
            int k0_ = ((kt) & 7) * 32;                                          \
            _Pragma("unroll")                                                   \
            for (int i = 0; i < 2; ++i) {                                       \
                int vsel = (i == 0) ? (ph_ ? 3 : 0) : (ph_ ? 1 : 2);            \
                const void* g = a + (((size_t)vsel * BC + bcr) * MMAX + m) * NLAT \
                                  + k0_ + (ch4 ^ (bcr & 3)) * 8;                \
                gload16(g, Ab[buf] + wid * 1024 + i * 8192);                    \
            }                                                                   \
        }

    uint4 wvv;
    #define WLOAD(kt)                                                           \
        {                                                                       \
            int ph_ = (kt) >> 3;                                                \
            int k0_ = ((kt) & 7) * 32;                                          \
            wvv = *(const uint4*)(wbf + (((size_t)ph_ * MMAX + m) * LMAX + l0 + lB) * NLAT \
                                     + k0_ + chB * 8);                          \
        }
    #define BWRITE(buf)                                                         \
        {                                                                       \
            *(uint4*)(Bb[buf] + lB * 80 + chB * 16) = wvv;                      \
        }
    #define MFMA_PHASE(ACC)                                                     \
        {                                                                       \
            bf16x8 bfr[4];                                                      \
            _Pragma("unroll")                                                   \
            for (int lt = 0; lt < 4; ++lt)                                      \
                bfr[lt] = *(const bf16x8*)(bb + (q * 64 + lt * 16 + r15) * 80 + hi * 16); \
            _Pragma("unroll")                                                   \
            for (int bt = 0; bt < 4; ++bt) {                                    \
                bf16x8 af = *(const bf16x8*)(ab + (o * 128 + h * 64 + bt * 16 + r15) * 64 \
                                               + ((hi * 16) ^ ((r15 & 3) << 4))); \
                _Pragma("unroll")                                               \
                for (int lt = 0; lt < 4; ++lt)                                  \
                    ACC[bt][lt] = __builtin_amdgcn_mfma_f32_16x16x32_bf16(af, bfr[lt], ACC[bt][lt], 0, 0, 0); \
            }                                                                   \
        }

    STAGE_A(0, 0);
    WLOAD(0);
    __syncthreads();
    BWRITE(0);

    for (int kt2 = 0; kt2 < 16; ++kt2) {
        int cur = kt2 & 1;
        if (kt2 < 15) WLOAD(kt2 + 1);
        __syncthreads();
        if (kt2 < 15) STAGE_A(cur ^ 1, kt2 + 1);

        const unsigned char* bb = Bb[cur];
        const unsigned char* ab = Ab[cur];
        if (kt2 < 8) MFMA_PHASE(accLo) else MFMA_PHASE(accHi);

        if (kt2 < 15) BWRITE(cur ^ 1);
    }

    #pragma unroll
    for (int bt = 0; bt < 4; ++bt) {
        #pragma unroll
        for (int lt = 0; lt < 4; ++lt) {
            #pragma unroll
            for (int j = 0; j < 4; ++j) {
                int bc = h * 64 + bt * 16 + hi * 4 + j;
                int l  = l0 + q * 64 + lt * 16 + r15;
                float lo = accLo[bt][lt][j];
                float hh = accHi[bt][lt][j];
                float val = (o == 0) ? (lo - hh) : (0.0f - (lo + hh));
                if (MODE == 0) {
                    __hip_bfloat16* outs = (__hip_bfloat16*)outv;
                    outs[(((size_t)m * 2 + o) * BC + bc) * LMAX + l] = __float2bfloat16(val);
                } else {
                    float* out = (float*)outv;
                    out[(((size_t)bc * 2 + o) * LMAX + l) * MMAX + m] = val;
                }
            }
        }
    }
    #undef STAGE_A
    #undef WLOAD
    #undef BWRITE
    #undef MFMA_PHASE
}

// ---------------------------------------------------------------------------
// K2 v4 (r22): fp32-w contraction — fallback when ws can't hold wbf.
// ---------------------------------------------------------------------------
template <int MODE>
__global__ __launch_bounds__(1024, 1) void contract_mfma(const unsigned short* __restrict__ a,
                                                         const float* __restrict__ w,
                                                         void* __restrict__ outv)
{
    __shared__ __align__(16) unsigned char Ab[2][16384];
    __shared__ __align__(16) unsigned char Bb[2][40960];
    int m  = blockIdx.x;
    int t = threadIdx.x;
    int wid = t >> 6, lane = t & 63;
    int o = wid >> 3, h = (wid >> 2) & 1, q = wid & 3;
    int r15 = lane & 15, hi = lane >> 4;

    f32x4 acc[4][4] = {};

    int pl  = t >> 9;
    int bcr = (t >> 2) & 127;
    int ch4 = t & 3;
    int lB  = t >> 2;
    int chB = t & 3;

    #define STAGE_A(buf, kt)                                                    \
        {                                                                       \
            int ph_ = (kt) >> 3;                                                \
            int k0_ = ((kt) & 7) * 32;                                          \
            int vsel = (pl == 0) ? (ph_ ? 3 : 0) : (ph_ ? 1 : 2);               \
            const void* g = a + (((size_t)vsel * BC + bcr) * MMAX + m) * NLAT   \
                              + k0_ + (ch4 ^ (bcr & 3)) * 8;                    \
            gload16(g, Ab[buf] + wid * 1024);                                   \
        }

    float4 wreg0, wreg1;
    #define WLOAD(kt)                                                           \
        {                                                                       \
            int ph_ = (kt) >> 3;                                                \
            int k0_ = ((kt) & 7) * 32;                                          \
            const float* wp = w + (((size_t)ph_ * MMAX + m) * LMAX + lB) * NLAT \
                                + k0_ + chB * 8;                                \
            wreg0 = *(const float4*)(wp);                                       \
            wreg1 = *(const float4*)(wp + 4);                                   \
        }
    #define BWRITE(buf)                                                         \
        {                                                                       \
            uint4 vv;                                                           \
            vv.x = bfpack2(wreg0.x, wreg0.y); vv.y = bfpack2(wreg0.z, wreg0.w); \
            vv.z = bfpack2(wreg1.x, wreg1.y); vv.w = bfpack2(wreg1.z, wreg1.w); \
            *(uint4*)(Bb[buf] + lB * 80 + chB * 16) = vv;                       \
            uint4 vn;                                                           \
            vn.x = vv.x ^ 0x80008000u; vn.y = vv.y ^ 0x80008000u;               \
            vn.z = vv.z ^ 0x80008000u; vn.w = vv.w ^ 0x80008000u;               \
            *(uint4*)(Bb[buf] + 20480 + lB * 80 + chB * 16) = vn;               \
        }

    STAGE_A(0, 0);
    WLOAD(0);
    __syncthreads();
    BWRITE(0);

    for (int kt2 = 0; kt2 < 16; ++kt2) {
        int cur = kt2 & 1;
        if (kt2 < 15) WLOAD(kt2 + 1);
        __syncthreads();
        if (kt2 < 15) STAGE_A(cur ^ 1, kt2 + 1);

        const unsigned char* bb = Bb[cur] + ((o == 0 && kt2 >= 8) ? 20480 : 0);
        const unsigned char* ab = Ab[cur];
        bf16x8 bfr[4];
        #pragma unroll
        for (int lt = 0; lt < 4; ++lt)
            bfr[lt] = *(const bf16x8*)(bb + (q * 64 + lt * 16 + r15) * 80 + hi * 16);
        #pragma unroll
        for (int bt = 0; bt < 4; ++bt) {
            bf16x8 af = *(const bf16x8*)(ab + (o * 128 + h * 64 + bt * 16 + r15) * 64
                                           + ((hi * 16) ^ ((r15 & 3) << 4)));
            #pragma unroll
            for (int lt = 0; lt < 4; ++lt)
                acc[bt][lt] = __builtin_amdgcn_mfma_f32_16x16x32_bf16(af, bfr[lt], acc[bt][lt], 0, 0, 0);
        }

        if (kt2 < 15) BWRITE(cur ^ 1);
    }

    #pragma unroll
    for (int bt = 0; bt < 4; ++bt) {
        #pragma unroll
        for (int lt = 0; lt < 4; ++lt) {
            #pragma unroll
            for (int j = 0; j < 4; ++j) {
                int bc = h * 64 + bt * 16 + hi * 4 + j;
                int l  = q * 64 + lt * 16 + r15;
                float av = acc[bt][lt][j];
                float val = (o == 0) ? av : (0.0f - av);
                if (MODE == 0) {
                    __hip_bfloat16* outs = (__hip_bfloat16*)outv;
                    outs[(((size_t)m * 2 + o) * BC + bc) * LMAX + l] = __float2bfloat16(val);
                } else {
                    float* out = (float*)outv;
                    out[(((size_t)bc * 2 + o) * LMAX + l) * MMAX + m] = val;
                }
            }
        }
    }
    #undef STAGE_A
    #undef WLOAD
    #undef BWRITE
}

// ---------------------------------------------------------------------------
// K3: transpose outs[m][o][bc][l] bf16 -> out[bc][o][l][m] fp32 (validated).
// ---------------------------------------------------------------------------
__global__ __launch_bounds__(256) void transpose_out(const unsigned short* __restrict__ outs,
                                                     float* __restrict__ out)
{
    __shared__ float tile[32][65];
    int mt = blockIdx.x;            // 0..8
    int lt = blockIdx.y;            // 0..3
    int z  = blockIdx.z;            // 0..255
    int bc = z >> 1, o = z & 1;
    int t = threadIdx.x;

    {
        int r = t >> 3, c0 = (t & 7) * 8;
        int mm = mt * 32 + r;
        if (mm < MMAX) {
            const unsigned short* src = outs + (((size_t)mm * 2 + o) * BC + bc) * LMAX + lt * 64 + c0;
            uint4 v = *(const uint4*)src;
            const unsigned short* u = (const unsigned short*)&v;
            #pragma unroll
            for (int i = 0; i < 8; ++i)
                tile[r][c0 + i] = __bfloat162float(__builtin_bit_cast(__hip_bfloat16, u[i]));
        }
    }
    __syncthreads();
    {
        int l = t >> 2, mc = (t & 3) * 8;
        float* dst = out + (((size_t)bc * 2 + o) * LMAX + lt * 64 + l) * MMAX + mt * 32 + mc;
        #pragma unroll
        for (int i = 0; i < 8; ++i) {
            int mm = mt * 32 + mc + i;
            if (mm < MMAX) dst[i] = tile[mc + i][l];
        }
    }
}

// ---------------------------------------------------------------------------
// Legacy proven path (round 9) — fallback for small ws.
// ---------------------------------------------------------------------------
#define PER_BC ((size_t)4 * MMAX * NLAT * sizeof(__hip_bfloat16))

__global__ __launch_bounds__(256) void dft_legacy(const float* __restrict__ x,
                                                  __hip_bfloat16* __restrict__ a,
                                                  int bc0, int nbc)
{
    __shared__ float  xs[512];
    __shared__ float2 tw[512];
    int t = threadIdx.x;
    int b = blockIdx.x;
    int lat = b & (NLAT - 1);
    int comp = (b >> 8) & 1;
    int bcl = b >> 9;
    int bc = bc0 + bcl;
    const float* xr = x + (((size_t)bc * 2 + comp) * NLAT + lat) * NLON;
    for (int j = t; j < 512; j += 256) {
        xs[j] = xr[j];
        float ang = -6.283185307179586f * (float)j / 512.0f;
        float sn, cs; sincosf(ang, &sn, &cs);
        tw[j] = make_float2(cs, sn);
    }
    __syncthreads();
    const float scale = 6.283185307179586f / 512.0f;
    size_t VS = (size_t)nbc * MMAX * NLAT;
    __hip_bfloat16* p0 = a + (size_t)(comp * 2) * VS + (size_t)bcl * MMAX * NLAT + lat;
    __hip_bfloat16* p1 = p0 + VS;
    for (int m = t; m < MMAX; m += 256) {
        float accr = 0.f, acci = 0.f;
        int j = 0;
        for (int n = 0; n < 512; ++n) {
            float xv = xs[n]; float2 wv = tw[j];
            accr += xv * wv.x; acci += xv * wv.y;
            j = (j + m) & 511;
        }
        p0[(size_t)m * NLAT] = __float2bfloat16(accr * scale);
        p1[(size_t)m * NLAT] = __float2bfloat16(acci * scale);
    }
}

__global__ __launch_bounds__(256) void contract_legacy(const __hip_bfloat16* __restrict__ a,
                                                       const float* __restrict__ w,
                                                       float* __restrict__ out,
                                                       int bc0, int nbc)
{
    __shared__ float w0s[16][NLAT + 1];
    __shared__ float w1s[16][NLAT + 1];
    __shared__ float as[4][4][NLAT + 1];
    __shared__ float2 red2[256];
    int tid = threadIdx.x;
    int m = blockIdx.x, l0 = blockIdx.y * 16, bct = blockIdx.z * 4;
    const float* w0g = w + ((size_t)m * LMAX + l0) * NLAT;
    const float* w1g = w0g + (size_t)MMAX * LMAX * NLAT;
    for (int idx = tid; idx < 16 * NLAT; idx += 256) {
        int l = idx >> 8, k = idx & 255;
        w0s[l][k] = w0g[(size_t)l * NLAT + k];
        w1s[l][k] = w1g[(size_t)l * NLAT + k];
    }
    size_t VS = (size_t)nbc * MMAX * NLAT;
    for (int idx = tid; idx < 4 * 4 * NLAT; idx += 256) {
        int v = idx >> 10, bl = (idx >> 8) & 3, k = idx & 255;
        int bls = bct + bl; if (bls > nbc - 1) bls = nbc - 1;
        as[v][bl][k] = __bfloat162float(a[(size_t)v * VS + ((size_t)bls * MMAX + m) * NLAT + k]);
    }
    __syncthreads();
    int l = tid & 15, b = (tid >> 4) & 3, kseg = tid >> 6;
    float acc0 = 0.f, acc2 = 0.f;
    int kbeg = kseg * 64;
    #pragma unroll 8
    for (int k = kbeg; k < kbeg + 64; ++k) {
        float tr = as[0][b][k], ti = as[1][b][k], pr = as[2][b][k], pi = as[3][b][k];
        float w0 = w0s[l][k], w1 = w1s[l][k];
        acc0 += tr * w0 - pi * w1;
        acc2 -= ti * w1 + pr * w0;
    }
    red2[tid] = make_float2(acc0, acc2);
    __syncthreads();
    if (kseg == 0 && (bct + b) < nbc) {
        #pragma unroll
        for (int s = 1; s < 4; ++s) {
            float2 r = red2[tid + 64 * s];
            acc0 += r.x; acc2 += r.y;
        }
        int bc = bc0 + bct + b;
        out[(((size_t)bc * 2 + 0) * LMAX + (l0 + l)) * MMAX + m] = acc0;
        out[(((size_t)bc * 2 + 1) * LMAX + (l0 + l)) * MMAX + m] = acc2;
    }
}

extern "C" void kernel_launch(void* const* d_in, const int* in_sizes, int n_in,
                              void* d_out, int out_size, void* d_ws, size_t ws_size,
                              hipStream_t stream)
{
    const float* x = (const float*)d_in[0];
    const float* w = (const float*)d_in[1];
    if (n_in >= 2) {
        long long s0 = (long long)in_sizes[0];
        if (s0 == (long long)W_ELEMS || s0 == W_BYTES) {
            w = (const float*)d_in[0];
            x = (const float*)d_in[1];
        }
    }
    float* out = (float*)d_out;

    if (ws_size >= F_BYTES + A_BYTES) {
        unsigned short* F = (unsigned short*)d_ws;
        unsigned short* a = (unsigned short*)((char*)d_ws + F_BYTES);
        bool have_outs = ws_size >= F_BYTES + A_BYTES + OUTS_BYTES;
        bool have_wbf  = ws_size >= F_BYTES + A_BYTES + OUTS_BYTES + WBF_BYTES;
        unsigned short* outs = (unsigned short*)((char*)d_ws + F_BYTES + A_BYTES);
        unsigned short* wbf  = (unsigned short*)((char*)d_ws + F_BYTES + A_BYTES + OUTS_BYTES);

        hipLaunchKernelGGL(f_init, dim3(FM, 2), dim3(256), 0, stream, F);
        hipLaunchKernelGGL(dft_mfma, dim3(256, 2), dim3(512), 0, stream,
                           x, F, a, w, have_wbf ? wbf : (unsigned short*)nullptr);
        if (have_outs) {
            if (have_wbf) {
                hipLaunchKernelGGL((contract_bf<0>), dim3(MMAX, 2), dim3(512), 0, stream,
                                   a, wbf, (void*)outs);
            } else {
                hipLaunchKernelGGL((contract_mfma<0>), dim3(MMAX), dim3(1024), 0, stream,
                                   a, w, (void*)outs);
            }
            hipLaunchKernelGGL(transpose_out, dim3(9, 4, 256), dim3(256), 0, stream,
                               outs, out);
        } else {
            hipLaunchKernelGGL((contract_mfma<1>), dim3(MMAX), dim3(1024), 0, stream,
                               a, w, (void*)out);
        }
    } else {
        __hip_bfloat16* a = (__hip_bfloat16*)d_ws;
        int nbc = 1;
        for (int c = 128; c >= 1; c >>= 1)
            if (PER_BC * (size_t)c <= ws_size) { nbc = c; break; }
        int nchunks = BC / nbc;
        for (int cc = 0; cc < nchunks; ++cc) {
            int bc0 = cc * nbc;
            hipLaunchKernelGGL(dft_legacy, dim3(nbc * 2 * NLAT), dim3(256), 0, stream,
                               x, a, bc0, nbc);
            hipLaunchKernelGGL(contract_legacy, dim3(MMAX, LMAX / 16, (nbc + 3) / 4),
                               dim3(256), 0, stream, a, w, out, bc0, nbc);
        }
    }
}

// Round 24
// 192.017 us; speedup vs baseline: 1.1941x; 1.1941x over previous
//
#include <hip/hip_runtime.h>
#include <hip/hip_bf16.h>
#include <math.h>

#define NLAT 256
#define NLON 512
#define LMAX 256
#define MMAX 257
#define BC   128

#define X_ELEMS 33554432
#define W_ELEMS 33685504
#define W_BYTES (W_ELEMS * 4LL)

#define FM    288                      // padded m rows for F
#define F_BYTES  ((size_t)2*FM*512*2)                    // 589,824
#define A_BYTES  ((size_t)4*BC*MMAX*NLAT*2)              // 67,371,008
#define OUTS_BYTES ((size_t)MMAX*2*BC*LMAX*2)            // 33,685,504

typedef short bf16x8 __attribute__((ext_vector_type(8)));
typedef float f32x4  __attribute__((ext_vector_type(4)));

__device__ __forceinline__ unsigned int bfpack2(float a, float b) {
    unsigned short lo = __builtin_bit_cast(unsigned short, __float2bfloat16(a));
    unsigned short hi = __builtin_bit_cast(unsigned short, __float2bfloat16(b));
    return (unsigned int)lo | ((unsigned int)hi << 16);
}
__device__ __forceinline__ unsigned short bf16bits(float a) {
    return __builtin_bit_cast(unsigned short, __float2bfloat16(a));
}
__device__ __forceinline__ void gload16(const void* g, void* l) {
    __builtin_amdgcn_global_load_lds(
        (const __attribute__((address_space(1))) unsigned int*)g,
        (__attribute__((address_space(3))) unsigned int*)l, 16, 0, 0);
}

// ---------------------------------------------------------------------------
// K0: build DFT matrix F[o][mm][n] bf16, scale 2*pi/512 folded in.
// ---------------------------------------------------------------------------
__global__ __launch_bounds__(256) void f_init(unsigned short* __restrict__ F)
{
    int mm = blockIdx.x, o = blockIdx.y, t = threadIdx.x;
    const float s = 6.283185307179586f / 512.0f;
    for (int c = 0; c < 2; ++c) {
        int n = t * 2 + c;
        float val = 0.0f;
        if (mm < MMAX) {
            int j = (mm * n) & 511;
            float ang = 6.283185307179586f * (float)j / 512.0f;
            float sn, cs; __sincosf(ang, &sn, &cs);
            val = (o == 0) ? s * cs : -s * sn;
        }
        F[((size_t)o * FM + mm) * 512 + n] =
            __builtin_bit_cast(unsigned short, __float2bfloat16(val));
    }
}

// ---------------------------------------------------------------------------
// K1 v10: DFT via MFMA (validated r21; reverted exactly — no w-conv epilogue).
// ---------------------------------------------------------------------------
__global__ __launch_bounds__(512, 1) void dft_mfma(const float* __restrict__ x,
                                                   const unsigned short* __restrict__ F,
                                                   unsigned short* __restrict__ aout)
{
    __shared__ __align__(16) unsigned char fl[2][32768];   // 64KB; prologue uses as xl
    unsigned char* xl = (unsigned char*)fl;

    int bcc = blockIdx.x;           // 0..255
    int kh  = blockIdx.y;           // 0..1
    int bc = bcc >> 1, comp = bcc & 1;
    int t = threadIdx.x;
    int wid = t >> 6, lane = t & 63;

    int o = wid >> 2, kt = wid & 3;
    int r15 = lane & 15, hi = lane >> 4;
    int klocal = kt * 16 + r15;
    unsigned braw = (unsigned)klocal * 1024u;
    unsigned bswz = (unsigned)(klocal & 15) << 4;

    bf16x8 barr0[16], barr1[16];
    #pragma unroll
    for (int s = 0; s < 2; ++s) {
        const float* xg = x + ((size_t)bcc * NLAT + kh * 128 + s * 64) * NLON;
        #pragma unroll
        for (int p = 0; p < 8; ++p) {
            int row = wid * 8 + p;
            const float* src = xg + (size_t)row * NLON + lane * 8;
            float4 f0 = *(const float4*)(src);
            float4 f1 = *(const float4*)(src + 4);
            uint4 v;
            v.x = bfpack2(f0.x, f0.y); v.y = bfpack2(f0.z, f0.w);
            v.z = bfpack2(f1.x, f1.y); v.w = bfpack2(f1.z, f1.w);
            unsigned off = ((unsigned)row * 1024u + (unsigned)lane * 16u)
                           ^ ((unsigned)(row & 15) << 4);
            *(uint4*)(xl + off) = v;
        }
        __syncthreads();
        #pragma unroll
        for (int nt = 0; nt < 16; ++nt) {
            unsigned c0 = (unsigned)(nt * 64 + hi * 16);
            bf16x8 v = *(const bf16x8*)(xl + ((braw + c0) ^ bswz));
            if (s == 0) barr0[nt] = v; else barr1[nt] = v;
        }
        __syncthreads();
    }

    const unsigned char* Fb = (const unsigned char*)F;
    unsigned gcol = ((unsigned)lane * 16u);

    #define STAGE_F(buf, mt)                                                  \
        {                                                                     \
            _Pragma("unroll")                                                 \
            for (int p = 0; p < 4; ++p) {                                     \
                int fr = wid * 4 + p;                                         \
                int o2 = fr >> 4, mr = fr & 15;                               \
                size_t grow = (size_t)o2 * FM + (mt) * 16 + mr;               \
                const void* g = Fb + grow * 1024u                             \
                                + (gcol ^ ((unsigned)(fr & 15) << 4));        \
                gload16(g, (unsigned char*)fl[buf] + (unsigned)fr * 1024u);   \
            }                                                                 \
        }

    STAGE_F(0, 0);
    __syncthreads();

    unsigned arow = (unsigned)(o * 16 + r15);
    unsigned abase = arow * 1024u;
    unsigned aswz = (unsigned)r15 << 4;
    unsigned short* ao = aout;
    int v = comp * 2 + o;

    for (int mt = 0; mt < 17; ++mt) {
        int cur = mt & 1;
        if (mt < 16) STAGE_F(cur ^ 1, mt + 1);

        const unsigned char* fb = fl[cur];
        f32x4 accA0 = {0.f,0.f,0.f,0.f}, accA1 = {0.f,0.f,0.f,0.f};
        f32x4 accB0 = {0.f,0.f,0.f,0.f}, accB1 = {0.f,0.f,0.f,0.f};
        #pragma unroll
        for (int nt = 0; nt < 16; nt += 2) {
            unsigned c0 = (unsigned)(nt * 64 + hi * 16);
            bf16x8 a0 = *(const bf16x8*)(fb + ((abase + c0)       ^ aswz));
            bf16x8 a1 = *(const bf16x8*)(fb + ((abase + c0 + 64u) ^ aswz));
            accA0 = __builtin_amdgcn_mfma_f32_16x16x32_bf16(a0, barr0[nt],     accA0, 0, 0, 0);
            accB0 = __builtin_amdgcn_mfma_f32_16x16x32_bf16(a0, barr1[nt],     accB0, 0, 0, 0);
            accA1 = __builtin_amdgcn_mfma_f32_16x16x32_bf16(a1, barr0[nt + 1], accA1, 0, 0, 0);
            accB1 = __builtin_amdgcn_mfma_f32_16x16x32_bf16(a1, barr1[nt + 1], accB1, 0, 0, 0);
        }
        #pragma unroll
        for (int j = 0; j < 4; ++j) {
            accA0[j] += accA1[j];
            accB0[j] += accB1[j];
        }

        #pragma unroll
        for (int j = 0; j < 4; ++j) {
            int mm0 = mt * 16 + hi * 4 + j;
            if (mm0 < MMAX) {
                size_t base = (((size_t)v * BC + bc) * MMAX + mm0) * NLAT + kh * 128;
                ao[base + klocal]      = bf16bits(accA0[j]);
                ao[base + klocal + 64] = bf16bits(accB0[j]);
            }
        }
        __syncthreads();
    }
    #undef STAGE_F
}

// ---------------------------------------------------------------------------
// K2 v8: contraction via MFMA. v3 skeleton (phase-split accLo/accHi, fp32 w,
// XOR-swizzled A via gload_lds, 80B-row B — all r19/r20-validated) with
// 2 k-tiles PER BARRIER PHASE: 8 iterations, 2x staged bytes and 32 MFMA per
// phase -> doubles the stage-issue->drain in-flight window, halves barriers.
// grid (m:257, lh:2), 512 thr = 8 waves (o:2, h:2, q:2).
// ---------------------------------------------------------------------------
template <int MODE>
__global__ __launch_bounds__(512, 1) void contract_mfma(const unsigned short* __restrict__ a,
                                                        const float* __restrict__ w,
                                                        void* __restrict__ outv)
{
    __shared__ __align__(16) unsigned char Ab[2][32768];   // [sub:2][pl:2 x 128 rows][64B], swz
    __shared__ __align__(16) unsigned char Bb[2][20480];   // [sub:2][128 l][80B rows]
    int m  = blockIdx.x;
    int lh = blockIdx.y;            // 0..1
    int t = threadIdx.x;
    int wid = t >> 6, lane = t & 63;
    int o = wid >> 2, h = (wid >> 1) & 1, q = wid & 1;
    int r15 = lane & 15, hi = lane >> 4;
    int l0 = lh * 128;

    f32x4 accLo[4][4] = {};
    f32x4 accHi[4][4] = {};

    int bcr = t >> 2, ch4 = t & 3;          // A staging: 4 thr/row, 16B each
    int lB  = t >> 2, chB = t & 3;          // B staging: 4 thr/row

    // stage k-tiles (ii*2, ii*2+1); phase = ii>>2 selects planes
    #define STAGE_A2(buf, ii)                                                   \
        {                                                                       \
            int ph_ = (ii) >> 2;                                                \
            _Pragma("unroll")                                                   \
            for (int sub = 0; sub < 2; ++sub) {                                 \
                int k0_ = (((ii) & 3) * 2 + sub) * 32;                          \
                _Pragma("unroll")                                               \
                for (int i = 0; i < 2; ++i) {                                   \
                    int vsel = (i == 0) ? (ph_ ? 3 : 0) : (ph_ ? 1 : 2);        \
                    const void* g = a + (((size_t)vsel * BC + bcr) * MMAX + m) * NLAT \
                                      + k0_ + (ch4 ^ (bcr & 3)) * 8;            \
                    gload16(g, Ab[buf] + sub * 16384 + i * 8192 + wid * 1024);  \
                }                                                               \
            }                                                                   \
        }

    float4 wr[4];
    #define WLOAD2(ii)                                                          \
        {                                                                       \
            int ph_ = (ii) >> 2;                                                \
            _Pragma("unroll")                                                   \
            for (int sub = 0; sub < 2; ++sub) {                                 \
                int k0_ = (((ii) & 3) * 2 + sub) * 32;                          \
                const float* wp = w + (((size_t)ph_ * MMAX + m) * LMAX + l0 + lB) * NLAT \
                                    + k0_ + chB * 8;                            \
                wr[sub * 2]     = *(const float4*)(wp);                         \
                wr[sub * 2 + 1] = *(const float4*)(wp + 4);                     \
            }                                                                   \
        }
    #define BWRITE2(buf)                                                        \
        {                                                                       \
            _Pragma("unroll")                                                   \
            for (int sub = 0; sub < 2; ++sub) {                                 \
                uint4 vv;                                                       \
                vv.x = bfpack2(wr[sub * 2].x,     wr[sub * 2].y);               \
                vv.y = bfpack2(wr[sub * 2].z,     wr[sub * 2].w);               \
                vv.z = bfpack2(wr[sub * 2 + 1].x, wr[sub * 2 + 1].y);           \
                vv.w = bfpack2(wr[sub * 2 + 1].z, wr[sub * 2 + 1].w);           \
                *(uint4*)(Bb[buf] + sub * 10240 + lB * 80 + chB * 16) = vv;     \
            }                                                                   \
        }
    #define MFMA_PHASE2(ACC)                                                    \
        {                                                                       \
            _Pragma("unroll")                                                   \
            for (int sub = 0; sub < 2; ++sub) {                                 \
                const unsigned char* bbs = bb + sub * 10240;                    \
                const unsigned char* abs_ = ab + sub * 16384;                   \
                bf16x8 bfr[4];                                                  \
                _Pragma("unroll")                                               \
                for (int lt = 0; lt < 4; ++lt)                                  \
                    bfr[lt] = *(const bf16x8*)(bbs + (q * 64 + lt * 16 + r15) * 80 + hi * 16); \
                _Pragma("unroll")                                               \
                for (int bt = 0; bt < 4; ++bt) {                                \
                    bf16x8 af = *(const bf16x8*)(abs_ + (o * 128 + h * 64 + bt * 16 + r15) * 64 \
                                                   + ((hi * 16) ^ ((r15 & 3) << 4))); \
                    _Pragma("unroll")                                           \
                    for (int lt = 0; lt < 4; ++lt)                              \
                        ACC[bt][lt] = __builtin_amdgcn_mfma_f32_16x16x32_bf16(af, bfr[lt], ACC[bt][lt], 0, 0, 0); \
                }                                                               \
            }                                                                   \
        }

    // prologue: stage phase-pair 0 into buf0
    STAGE_A2(0, 0);
    WLOAD2(0);
    __syncthreads();            // drains A(0) gloads + wr loads
    BWRITE2(0);

    for (int ii = 0; ii < 8; ++ii) {
        int cur = ii & 1;
        if (ii < 7) WLOAD2(ii + 1);            // private regs, pre-barrier OK
        __syncthreads();        // drains BWRITE2(cur) [lgkm] + STAGE_A2(cur) [vm]
        if (ii < 7) STAGE_A2(cur ^ 1, ii + 1); // hidden under MFMA below

        const unsigned char* bb = Bb[cur];
        const unsigned char* ab = Ab[cur];
        if (ii < 4) MFMA_PHASE2(accLo) else MFMA_PHASE2(accHi);

        if (ii < 7) BWRITE2(cur ^ 1);          // waits wr vmcnt (hidden by MFMA)
    }

    #pragma unroll
    for (int bt = 0; bt < 4; ++bt) {
        #pragma unroll
        for (int lt = 0; lt < 4; ++lt) {
            #pragma unroll
            for (int j = 0; j < 4; ++j) {
                int bc = h * 64 + bt * 16 + hi * 4 + j;
                int l  = l0 + q * 64 + lt * 16 + r15;
                float lo = accLo[bt][lt][j];
                float hh = accHi[bt][lt][j];
                float val = (o == 0) ? (lo - hh) : (0.0f - (lo + hh));
                if (MODE == 0) {
                    __hip_bfloat16* outs = (__hip_bfloat16*)outv;
                    outs[(((size_t)m * 2 + o) * BC + bc) * LMAX + l] = __float2bfloat16(val);
                } else {
                    float* out = (float*)outv;
                    out[(((size_t)bc * 2 + o) * LMAX + l) * MMAX + m] = val;
                }
            }
        }
    }
    #undef STAGE_A2
    #undef WLOAD2
    #undef BWRITE2
    #undef MFMA_PHASE2
}

// ---------------------------------------------------------------------------
// K3: transpose outs[m][o][bc][l] bf16 -> out[bc][o][l][m] fp32 (validated).
// ---------------------------------------------------------------------------
__global__ __launch_bounds__(256) void transpose_out(const unsigned short* __restrict__ outs,
                                                     float* __restrict__ out)
{
    __shared__ float tile[32][65];
    int mt = blockIdx.x;            // 0..8
    int lt = blockIdx.y;            // 0..3
    int z  = blockIdx.z;            // 0..255
    int bc = z >> 1, o = z & 1;
    int t = threadIdx.x;

    {
        int r = t >> 3, c0 = (t & 7) * 8;
        int mm = mt * 32 + r;
        if (mm < MMAX) {
            const unsigned short* src = outs + (((size_t)mm * 2 + o) * BC + bc) * LMAX + lt * 64 + c0;
            uint4 v = *(const uint4*)src;
            const unsigned short* u = (const unsigned short*)&v;
            #pragma unroll
            for (int i = 0; i < 8; ++i)
                tile[r][c0 + i] = __bfloat162float(__builtin_bit_cast(__hip_bfloat16, u[i]));
        }
    }
    __syncthreads();
    {
        int l = t >> 2, mc = (t & 3) * 8;
        float* dst = out + (((size_t)bc * 2 + o) * LMAX + lt * 64 + l) * MMAX + mt * 32 + mc;
        #pragma unroll
        for (int i = 0; i < 8; ++i) {
            int mm = mt * 32 + mc + i;
            if (mm < MMAX) dst[i] = tile[mc + i][l];
        }
    }
}

// ---------------------------------------------------------------------------
// Legacy proven path (round 9) — fallback for small ws.
// ---------------------------------------------------------------------------
#define PER_BC ((size_t)4 * MMAX * NLAT * sizeof(__hip_bfloat16))

__global__ __launch_bounds__(256) void dft_legacy(const float* __restrict__ x,
                                                  __hip_bfloat16* __restrict__ a,
                                                  int bc0, int nbc)
{
    __shared__ float  xs[512];
    __shared__ float2 tw[512];
    int t = threadIdx.x;
    int b = blockIdx.x;
    int lat = b & (NLAT - 1);
    int comp = (b >> 8) & 1;
    int bcl = b >> 9;
    int bc = bc0 + bcl;
    const float* xr = x + (((size_t)bc * 2 + comp) * NLAT + lat) * NLON;
    for (int j = t; j < 512; j += 256) {
        xs[j] = xr[j];
        float ang = -6.283185307179586f * (float)j / 512.0f;
        float sn, cs; sincosf(ang, &sn, &cs);
        tw[j] = make_float2(cs, sn);
    }
    __syncthreads();
    const float scale = 6.283185307179586f / 512.0f;
    size_t VS = (size_t)nbc * MMAX * NLAT;
    __hip_bfloat16* p0 = a + (size_t)(comp * 2) * VS + (size_t)bcl * MMAX * NLAT + lat;
    __hip_bfloat16* p1 = p0 + VS;
    for (int m = t; m < MMAX; m += 256) {
        float accr = 0.f, acci = 0.f;
        int j = 0;
        for (int n = 0; n < 512; ++n) {
            float xv = xs[n]; float2 wv = tw[j];
            accr += xv * wv.x; acci += xv * wv.y;
            j = (j + m) & 511;
        }
        p0[(size_t)m * NLAT] = __float2bfloat16(accr * scale);
        p1[(size_t)m * NLAT] = __float2bfloat16(acci * scale);
    }
}

__global__ __launch_bounds__(256) void contract_legacy(const __hip_bfloat16* __restrict__ a,
                                                       const float* __restrict__ w,
                                                       float* __restrict__ out,
                                                       int bc0, int nbc)
{
    __shared__ float w0s[16][NLAT + 1];
    __shared__ float w1s[16][NLAT + 1];
    __shared__ float as[4][4][NLAT + 1];
    __shared__ float2 red2[256];
    int tid = threadIdx.x;
    int m = blockIdx.x, l0 = blockIdx.y * 16, bct = blockIdx.z * 4;
    const float* w0g = w + ((size_t)m * LMAX + l0) * NLAT;
    const float* w1g = w0g + (size_t)MMAX * LMAX * NLAT;
    for (int idx = tid; idx < 16 * NLAT; idx += 256) {
        int l = idx >> 8, k = idx & 255;
        w0s[l][k] = w0g[(size_t)l * NLAT + k];
        w1s[l][k] = w1g[(size_t)l * NLAT + k];
    }
    size_t VS = (size_t)nbc * MMAX * NLAT;
    for (int idx = tid; idx < 4 * 4 * NLAT; idx += 256) {
        int v = idx >> 10, bl = (idx >> 8) & 3, k = idx & 255;
        int bls = bct + bl; if (bls > nbc - 1) bls = nbc - 1;
        as[v][bl][k] = __bfloat162float(a[(size_t)v * VS + ((size_t)bls * MMAX + m) * NLAT + k]);
    }
    __syncthreads();
    int l = tid & 15, b = (tid >> 4) & 3, kseg = tid >> 6;
    float acc0 = 0.f, acc2 = 0.f;
    int kbeg = kseg * 64;
    #pragma unroll 8
    for (int k = kbeg; k < kbeg + 64; ++k) {
        float tr = as[0][b][k], ti = as[1][b][k], pr = as[2][b][k], pi = as[3][b][k];
        float w0 = w0s[l][k], w1 = w1s[l][k];
        acc0 += tr * w0 - pi * w1;
        acc2 -= ti * w1 + pr * w0;
    }
    red2[tid] = make_float2(acc0, acc2);
    __syncthreads();
    if (kseg == 0 && (bct + b) < nbc) {
        #pragma unroll
        for (int s = 1; s < 4; ++s) {
            float2 r = red2[tid + 64 * s];
            acc0 += r.x; acc2 += r.y;
        }
        int bc = bc0 + bct + b;
        out[(((size_t)bc * 2 + 0) * LMAX + (l0 + l)) * MMAX + m] = acc0;
        out[(((size_t)bc * 2 + 1) * LMAX + (l0 + l)) * MMAX + m] = acc2;
    }
}

extern "C" void kernel_launch(void* const* d_in, const int* in_sizes, int n_in,
                              void* d_out, int out_size, void* d_ws, size_t ws_size,
                              hipStream_t stream)
{
    const float* x = (const float*)d_in[0];
    const float* w = (const float*)d_in[1];
    if (n_in >= 2) {
        long long s0 = (long long)in_sizes[0];
        if (s0 == (long long)W_ELEMS || s0 == W_BYTES) {
            w = (const float*)d_in[0];
            x = (const float*)d_in[1];
        }
    }
    float* out = (float*)d_out;

    if (ws_size >= F_BYTES + A_BYTES) {
        unsigned short* F = (unsigned short*)d_ws;
        unsigned short* a = (unsigned short*)((char*)d_ws + F_BYTES);
        hipLaunchKernelGGL(f_init, dim3(FM, 2), dim3(256), 0, stream, F);
        hipLaunchKernelGGL(dft_mfma, dim3(256, 2), dim3(512), 0, stream, x, F, a);
        if (ws_size >= F_BYTES + A_BYTES + OUTS_BYTES) {
            unsigned short* outs = (unsigned short*)((char*)d_ws + F_BYTES + A_BYTES);
            hipLaunchKernelGGL((contract_mfma<0>), dim3(MMAX, 2), dim3(512), 0, stream,
                               a, w, (void*)outs);
            hipLaunchKernelGGL(transpose_out, dim3(9, 4, 256), dim3(256), 0, stream,
                               outs, out);
        } else {
            hipLaunchKernelGGL((contract_mfma<1>), dim3(MMAX, 2), dim3(512), 0, stream,
                               a, w, (void*)out);
        }
    } else {
        __hip_bfloat16* a = (__hip_bfloat16*)d_ws;
        int nbc = 1;
        for (int c = 128; c >= 1; c >>= 1)
            if (PER_BC * (size_t)c <= ws_size) { nbc = c; break; }
        int nchunks = BC / nbc;
        for (int cc = 0; cc < nchunks; ++cc) {
            int bc0 = cc * nbc;
            hipLaunchKernelGGL(dft_legacy, dim3(nbc * 2 * NLAT), dim3(256), 0, stream,
                               x, a, bc0, nbc);
            hipLaunchKernelGGL(contract_legacy, dim3(MMAX, LMAX / 16, (nbc + 3) / 4),
                               dim3(256), 0, stream, a, w, out, bc0, nbc);
        }
    }
}